// Round 8
// baseline (254.515 us; speedup 1.0000x reference)
//
#include <hip/hip_runtime.h>
#include <hip/hip_fp16.h>

#define NB    4
#define NPTS  4096
#define DF    32      // D*C = K of the MFMA
#define CC    8
#define CO    16
#define KNN   16
#define TILE  128     // candidates per pipeline tile
#define NT    (NPTS/TILE)
#define FIFO_N 128    // per-row pending ring (max pending 63+64=127)
#define DSTR  17      // D-tile padded stride (floats): 2-way banks both dirs

typedef _Float16 f16x8 __attribute__((ext_vector_type(8)));
typedef float    f32x4 __attribute__((ext_vector_type(4)));

__device__ __forceinline__ unsigned sortable32(float f) {
    unsigned u = __float_as_uint(f);
    return u ^ ((unsigned)((int)u >> 31) | 0x80000000u);
}

// Full-wave ascending bitonic sort of one u32 per lane (verified R3-R7).
__device__ __forceinline__ unsigned bitonic_sort64(unsigned key, int lane) {
#pragma unroll
    for (int k = 2; k <= 64; k <<= 1) {
#pragma unroll
        for (int j = k >> 1; j > 0; j >>= 1) {
            unsigned o = __shfl_xor(key, j);
            bool up       = ((lane & k) == 0);
            bool lower    = ((lane & j) == 0);
            bool takeMin  = (lower == up);
            bool mineLess = key < o;
            if (takeMin != mineLess) key = o;
        }
    }
    return key;
}
__device__ __forceinline__ unsigned bitonic_clean64(unsigned v, int lane) {
#pragma unroll
    for (int j = 32; j > 0; j >>= 1) {
        unsigned o = __shfl_xor(v, j);
        bool lower = ((lane & j) == 0);
        v = lower ? min(v, o) : max(v, o);
    }
    return v;
}
__device__ __forceinline__ void merge_batch(unsigned& run, unsigned bk, int lane) {
    bk = bitonic_sort64(bk, lane);
    unsigned rev = __shfl(bk, 63 - lane);
    unsigned lo  = min(run, rev);
    run = bitonic_clean64(lo, lane);
}

// ---- prep: per-point squared norm (fp32) + half-packed copy of x ----
__global__ void prep_kernel(const float* __restrict__ x, float* __restrict__ sq,
                            __half* __restrict__ xh) {
    int i = blockIdx.x * 256 + threadIdx.x;          // 0 .. NB*NPTS-1
    const float4* p = (const float4*)(x + (size_t)i * DF);
    __half2* ho = (__half2*)(xh + (size_t)i * DF);
    float a = 0.f, b2 = 0.f;
#pragma unroll
    for (int f = 0; f < 8; ++f) {
        float4 v = p[f];
        a  = fmaf(v.x, v.x, a);  b2 = fmaf(v.y, v.y, b2);
        a  = fmaf(v.z, v.z, a);  b2 = fmaf(v.w, v.w, b2);
        ho[f * 2 + 0] = __floats2half2_rn(v.x, v.y);
        ho[f * 2 + 1] = __floats2half2_rn(v.z, v.w);
    }
    sq[i] = a + b2;
}

// ---- canonical-fp32 re-rank + output (verified R3-R7 verbatim) ----
__device__ __forceinline__ void rerank_and_emit(
    unsigned runv, int nn, const float* __restrict__ xb,
    const float (*w1n)[KNN], const float (*w2n)[CO],
    float* __restrict__ out, int bb, int lane) {

    int mym = (int)(runv & 0xFFFu);
    const float* rp = xb + (size_t)nn * DF;
    const float* cp = xb + (size_t)mym * DF;
    double dot64 = 0.0, sqm64 = 0.0, sqn64 = 0.0;
#pragma unroll
    for (int f = 0; f < DF; ++f) {
        double cv = (double)cp[f];
        double rv = (double)rp[f];
        dot64 = fma(rv, cv, dot64);
        sqm64 = fma(cv, cv, sqm64);
        sqn64 = fma(rv, rv, sqn64);
    }
    float dist32 = ((float)sqn64 + (float)sqm64) - 2.0f * (float)dot64;

    unsigned long long key =
        ((unsigned long long)sortable32(dist32) << 32) | (unsigned)mym;
#pragma unroll
    for (int k = 2; k <= 64; k <<= 1) {
#pragma unroll
        for (int j = k >> 1; j > 0; j >>= 1) {
            unsigned long long ok = __shfl_xor(key, j);
            bool up       = ((lane & k) == 0);
            bool lower    = ((lane & j) == 0);
            bool takeMin  = (lower == up);
            bool mineLess = (key < ok);
            if (takeMin != mineLess) key = ok;
        }
    }
    mym = (int)(key & 0xFFFFFFFFull);

    float wsum = 0.f;
#pragma unroll
    for (int k = 0; k < KNN; ++k) {
        int mk = __shfl(mym, k);                       // uniform
        float v = 0.f;
        if (lane < DF) v = xb[(size_t)mk * DF + lane]; // coalesced gather
        wsum = fmaf(v, w1n[lane & 7][k], wsum);        // lane = d*8+c
    }
    float ov = 0.f;
    const int d_ = lane >> 4, o_ = lane & 15;
#pragma unroll
    for (int c = 0; c < CC; ++c) {
        float wv = __shfl(wsum, d_ * CC + c);
        ov = fmaf(wv, w2n[c][o_], ov);
    }
    out[(size_t)(bb * NPTS + nn) * (4 * CO) + lane] = ov;
}

__global__ __launch_bounds__(256)
void wfm_kernel(const float* __restrict__ x, const __half* __restrict__ xh,
                const float* __restrict__ sqg, const float* __restrict__ w1,
                const float* __restrict__ w2, float* __restrict__ out) {
    const int tid  = threadIdx.x;
    const int lane = tid & 63;
    const int wave = tid >> 6;
    const int b    = blockIdx.x >> 8;           // 256 row-blocks per batch
    const int rblk = blockIdx.x & 255;
    const int n0   = rblk * 16;                 // 16 rows per block

    const float* xb  = x + (size_t)b * NPTS * DF;
    const float* sqb = sqg + b * NPTS;
    const uint4* xhs = (const uint4*)(xh + (size_t)b * NPTS * DF); // 16B slots

    __shared__ uint4    Abuf[2][TILE * 4];            // cand f16 tiles, chunk-XOR
    __shared__ float    Dl[2][TILE * DSTR];           // D[cand][row], stride 17
    __shared__ float    sq_l[2][TILE] __attribute__((aligned(16)));
    __shared__ unsigned fifo[4][4][FIFO_N];
    __shared__ float    w1n[CC][KNN];
    __shared__ float    w2n[CC][CO];
    __shared__ float    nrm[CC + CO];

    // ---- normalize weights ----
    if (tid < CC) {
        float s = 0.f;
        for (int k = 0; k < KNN; ++k) { float v = w1[tid * KNN + k]; s = fmaf(v, v, s); }
        nrm[tid] = sqrtf(s);
    } else if (tid < CC + CO) {
        int o = tid - CC; float s = 0.f;
        for (int c = 0; c < CC; ++c) { float v = w2[c * CO + o]; s = fmaf(v, v, s); }
        nrm[tid] = sqrtf(s);
    }
    __syncthreads();
    if (tid < CC * KNN) w1n[tid >> 4][tid & 15] = w1[tid] / nrm[tid >> 4];
    if (tid < CC * CO)  w2n[tid >> 4][tid & 15] = w2[tid] / nrm[CC + (tid & 15)];

    // ---- B-fragment: this block's 16 rows, scaled by -2, resident (4 VGPR) ----
    // B[k][n]: n = lane&15 -> row, k = (lane>>4)*8 + j
    f16x8 bfrag;
    {
        const uint4* rp = (const uint4*)(xh + ((size_t)b * NPTS + n0 + (lane & 15)) * DF
                                         + (lane >> 4) * 8);
        uint4 rv = *rp;
        const __half2 m2 = __floats2half2_rn(-2.f, -2.f);
        uint4 sc;
        sc.x = __builtin_bit_cast(unsigned, __hmul2(__builtin_bit_cast(__half2, rv.x), m2));
        sc.y = __builtin_bit_cast(unsigned, __hmul2(__builtin_bit_cast(__half2, rv.y), m2));
        sc.z = __builtin_bit_cast(unsigned, __hmul2(__builtin_bit_cast(__half2, rv.z), m2));
        sc.w = __builtin_bit_cast(unsigned, __hmul2(__builtin_bit_cast(__half2, rv.w), m2));
        bfrag = __builtin_bit_cast(f16x8, sc);
    }

    // ---- selection state: 4 rows per wave ----
    unsigned run[4] = {0xFFFFFFFFu, 0xFFFFFFFFu, 0xFFFFFFFFu, 0xFFFFFFFFu};
    unsigned T[4]   = {0xFFFFFFFFu, 0xFFFFFFFFu, 0xFFFFFFFFu, 0xFFFFFFFFu};
    int base[4] = {0,0,0,0}, cnt[4] = {0,0,0,0};
    unsigned* ffp[4] = { &fifo[wave][0][0], &fifo[wave][1][0],
                         &fifo[wave][2][0], &fifo[wave][3][0] };

    auto accept = [&](unsigned key, unsigned& rn, unsigned& Th,
                      int& bs, int& ct, unsigned* ff) {
        bool acc = key < Th;
        unsigned long long bal = __ballot(acc);
        if (bal) {                               // wave-uniform
            int pos = ct + (int)__popcll(bal & ((1ull << lane) - 1ull));
            if (acc) ff[(bs + pos) & (FIFO_N - 1)] = key;
            ct += (int)__popcll(bal);
            __builtin_amdgcn_wave_barrier();
            asm volatile("" ::: "memory");
            if (ct >= 64) {
                unsigned bk = ff[(bs + lane) & (FIFO_N - 1)];
                bs += 64; ct -= 64;
                merge_batch(rn, bk, lane);
                Th = __shfl(rn, 63);
            }
        }
    };

    // ---- prologue: stage tile 0 ----
    {
        // cand slot s: c=s>>2, j=s&3 stored at c*4 + (j^(c&3)); src linear
        uint4 p0 = xhs[tid];
        uint4 p1 = xhs[256 + tid];
        int c = tid >> 2, j = tid & 3;
        int dst = c * 4 + (j ^ (c & 3));
        Abuf[0][dst]       = p0;
        Abuf[0][dst + 256] = p1;
        if (tid < TILE) sq_l[0][tid] = sqb[tid];
    }
    __syncthreads();

    const int c16 = lane & 15, g = lane >> 4;

    // ---- pipelined scan: stage(i+1) | mfma(i) | select(i-1), 1 barrier/tile ----
#pragma unroll 1
    for (int i = 0; i < NT; ++i) {
        const int par = i & 1, nxt = par ^ 1;

        // prefetch tile i+1 (global, hidden under mfma+select)
        uint4 p0, p1; float sqpf = 0.f;
        if (i + 1 < NT) {
            p0 = xhs[(size_t)(i + 1) * (TILE * 4) + tid];
            p1 = xhs[(size_t)(i + 1) * (TILE * 4) + 256 + tid];
            if (tid < TILE) sqpf = sqb[(i + 1) * TILE + tid];
        }

        // mfma phase: this wave's 2 cand-subtiles (32 cands x 16 rows)
#pragma unroll
        for (int s = 0; s < 2; ++s) {
            const int cs = (wave * 2 + s) * 16;            // subtile base cand
            const int slot = (cs + c16) * 4 + (g ^ (c16 & 3));
            f16x8 af = ((const f16x8*)&Abuf[par][0])[slot]; // A: cands
            f32x4 cf = *(const f32x4*)&sq_l[par][cs + 4 * g]; // C: sq[cand]
            f32x4 pr = __builtin_amdgcn_mfma_f32_16x16x32_f16(af, bfrag, cf, 0, 0, 0);
            // pr[j] = dist[cand = cs+4g+j][row = c16]
            float* dw = &Dl[par][(cs + 4 * g) * DSTR + c16];
            dw[0 * DSTR] = pr[0];
            dw[1 * DSTR] = pr[1];
            dw[2 * DSTR] = pr[2];
            dw[3 * DSTR] = pr[3];
        }

        // selection phase on tile i-1 (all 16 rows' D complete, barrier'd)
        if (i > 0) {
            const int t0 = (i - 1) * TILE;
#pragma unroll
            for (int rr = 0; rr < 4; ++rr) {
                const int growr = wave * 4 + rr;
#pragma unroll
                for (int p = 0; p < 2; ++p) {
                    int c = p * 64 + lane;
                    float d = Dl[nxt][c * DSTR + growr];
                    unsigned key = (sortable32(d) & 0xFFFFF000u) | (unsigned)(t0 + c);
                    accept(key, run[rr], T[rr], base[rr], cnt[rr], ffp[rr]);
                }
            }
        }

        // stage tile i+1 into the buffer mfma just freed
        if (i + 1 < NT) {
            int c = tid >> 2, j = tid & 3;
            int dst = c * 4 + (j ^ (c & 3));
            Abuf[nxt][dst]       = p0;
            Abuf[nxt][dst + 256] = p1;
            if (tid < TILE) sq_l[nxt][tid] = sqpf;
        }
        __syncthreads();
    }

    // ---- final tile's selection ----
    {
        const int par = (NT - 1) & 1;
        const int t0 = (NT - 1) * TILE;
#pragma unroll
        for (int rr = 0; rr < 4; ++rr) {
            const int growr = wave * 4 + rr;
#pragma unroll
            for (int p = 0; p < 2; ++p) {
                int c = p * 64 + lane;
                float d = Dl[par][c * DSTR + growr];
                unsigned key = (sortable32(d) & 0xFFFFF000u) | (unsigned)(t0 + c);
                accept(key, run[rr], T[rr], base[rr], cnt[rr], ffp[rr]);
            }
        }
    }

    // ---- drain + canonical re-rank + emit (verified) ----
#pragma unroll
    for (int rr = 0; rr < 4; ++rr) {
        if (cnt[rr] > 0) {
            unsigned bk = (lane < cnt[rr])
                        ? ffp[rr][(base[rr] + lane) & (FIFO_N - 1)] : 0xFFFFFFFFu;
            merge_batch(run[rr], bk, lane);
        }
        rerank_and_emit(run[rr], n0 + wave * 4 + rr, xb, w1n, w2n, out, b, lane);
    }
}

extern "C" void kernel_launch(void* const* d_in, const int* in_sizes, int n_in,
                              void* d_out, int out_size, void* d_ws, size_t ws_size,
                              hipStream_t stream) {
    const float* x  = (const float*)d_in[0];
    const float* w1 = (const float*)d_in[1];
    const float* w2 = (const float*)d_in[2];
    float* out = (float*)d_out;

    float*  sq = (float*)d_ws;                                  // 64 KB
    __half* xh = (__half*)((char*)d_ws + (size_t)NB * NPTS * sizeof(float)); // 1 MB

    prep_kernel<<<NB * NPTS / 256, 256, 0, stream>>>(x, sq, xh);
    wfm_kernel<<<NB * (NPTS / 16), 256, 0, stream>>>(x, xh, sq, w1, w2, out);
}

// Round 9
// 252.428 us; speedup vs baseline: 1.0083x; 1.0083x over previous
//
#include <hip/hip_runtime.h>
#include <hip/hip_fp16.h>

#define NB    4
#define NPTS  4096
#define DF    32      // D*C = K of the MFMA
#define CC    8
#define CO    16
#define KNN   16
#define TILE  128     // candidates per pipeline tile
#define NT    (NPTS/TILE)
#define FIFO_N 128    // per-row pending ring (max pending 63+64=127)
#define DSTR  130     // Dl row stride (floats): 130%32=2 -> 2-way banks on r/w

typedef _Float16 f16x8 __attribute__((ext_vector_type(8)));
typedef float    f32x4 __attribute__((ext_vector_type(4)));

__device__ __forceinline__ unsigned sortable32(float f) {
    unsigned u = __float_as_uint(f);
    return u ^ ((unsigned)((int)u >> 31) | 0x80000000u);
}

// Full-wave ascending bitonic sort of one u32 per lane (verified R3-R8).
__device__ __forceinline__ unsigned bitonic_sort64(unsigned key, int lane) {
#pragma unroll
    for (int k = 2; k <= 64; k <<= 1) {
#pragma unroll
        for (int j = k >> 1; j > 0; j >>= 1) {
            unsigned o = __shfl_xor(key, j);
            bool up       = ((lane & k) == 0);
            bool lower    = ((lane & j) == 0);
            bool takeMin  = (lower == up);
            bool mineLess = key < o;
            if (takeMin != mineLess) key = o;
        }
    }
    return key;
}
__device__ __forceinline__ unsigned bitonic_clean64(unsigned v, int lane) {
#pragma unroll
    for (int j = 32; j > 0; j >>= 1) {
        unsigned o = __shfl_xor(v, j);
        bool lower = ((lane & j) == 0);
        v = lower ? min(v, o) : max(v, o);
    }
    return v;
}
__device__ __forceinline__ void merge_batch(unsigned& run, unsigned bk, int lane) {
    bk = bitonic_sort64(bk, lane);
    unsigned rev = __shfl(bk, 63 - lane);
    unsigned lo  = min(run, rev);
    run = bitonic_clean64(lo, lane);
}

// ---- prep: per-point squared norm (fp32) + half-packed copy of x ----
__global__ void prep_kernel(const float* __restrict__ x, float* __restrict__ sq,
                            __half* __restrict__ xh) {
    int i = blockIdx.x * 256 + threadIdx.x;          // 0 .. NB*NPTS-1
    const float4* p = (const float4*)(x + (size_t)i * DF);
    __half2* ho = (__half2*)(xh + (size_t)i * DF);
    float a = 0.f, b2 = 0.f;
#pragma unroll
    for (int f = 0; f < 8; ++f) {
        float4 v = p[f];
        a  = fmaf(v.x, v.x, a);  b2 = fmaf(v.y, v.y, b2);
        a  = fmaf(v.z, v.z, a);  b2 = fmaf(v.w, v.w, b2);
        ho[f * 2 + 0] = __floats2half2_rn(v.x, v.y);
        ho[f * 2 + 1] = __floats2half2_rn(v.z, v.w);
    }
    sq[i] = a + b2;
}

// ---- canonical-fp32 re-rank + output (verified R3-R8 verbatim) ----
__device__ __forceinline__ void rerank_and_emit(
    unsigned runv, int nn, const float* __restrict__ xb,
    const float (*w1n)[KNN], const float (*w2n)[CO],
    float* __restrict__ out, int bb, int lane) {

    int mym = (int)(runv & 0xFFFu);
    const float* rp = xb + (size_t)nn * DF;
    const float* cp = xb + (size_t)mym * DF;
    double dot64 = 0.0, sqm64 = 0.0, sqn64 = 0.0;
#pragma unroll
    for (int f = 0; f < DF; ++f) {
        double cv = (double)cp[f];
        double rv = (double)rp[f];
        dot64 = fma(rv, cv, dot64);
        sqm64 = fma(cv, cv, sqm64);
        sqn64 = fma(rv, rv, sqn64);
    }
    float dist32 = ((float)sqn64 + (float)sqm64) - 2.0f * (float)dot64;

    unsigned long long key =
        ((unsigned long long)sortable32(dist32) << 32) | (unsigned)mym;
#pragma unroll
    for (int k = 2; k <= 64; k <<= 1) {
#pragma unroll
        for (int j = k >> 1; j > 0; j >>= 1) {
            unsigned long long ok = __shfl_xor(key, j);
            bool up       = ((lane & k) == 0);
            bool lower    = ((lane & j) == 0);
            bool takeMin  = (lower == up);
            bool mineLess = (key < ok);
            if (takeMin != mineLess) key = ok;
        }
    }
    mym = (int)(key & 0xFFFFFFFFull);

    float wsum = 0.f;
#pragma unroll
    for (int k = 0; k < KNN; ++k) {
        int mk = __shfl(mym, k);                       // uniform
        float v = 0.f;
        if (lane < DF) v = xb[(size_t)mk * DF + lane]; // coalesced gather
        wsum = fmaf(v, w1n[lane & 7][k], wsum);        // lane = d*8+c
    }
    float ov = 0.f;
    const int d_ = lane >> 4, o_ = lane & 15;
#pragma unroll
    for (int c = 0; c < CC; ++c) {
        float wv = __shfl(wsum, d_ * CC + c);
        ov = fmaf(wv, w2n[c][o_], ov);
    }
    out[(size_t)(bb * NPTS + nn) * (4 * CO) + lane] = ov;
}

__global__ __launch_bounds__(512, 4)
void wfm_kernel(const float* __restrict__ x, const __half* __restrict__ xh,
                const float* __restrict__ sqg, const float* __restrict__ w1,
                const float* __restrict__ w2, float* __restrict__ out) {
    const int tid  = threadIdx.x;
    const int lane = tid & 63;
    const int wave = tid >> 6;                  // 0..7
    const int b    = blockIdx.x >> 8;           // 256 row-blocks per batch
    const int rblk = blockIdx.x & 255;
    const int n0   = rblk * 16;                 // 16 rows per block

    const float*  xb  = x + (size_t)b * NPTS * DF;
    const float*  sqb = sqg + b * NPTS;
    const __half* xcb = xh + (size_t)b * NPTS * DF;

    __shared__ float    Dl[2][16 * DSTR];       // D[row][cand], 2-way banks
    __shared__ unsigned fifo[8][2][FIFO_N];
    __shared__ float    w1n[CC][KNN];
    __shared__ float    w2n[CC][CO];
    __shared__ float    nrm[CC + CO];

    // ---- normalize weights ----
    if (tid < CC) {
        float s = 0.f;
        for (int k = 0; k < KNN; ++k) { float v = w1[tid * KNN + k]; s = fmaf(v, v, s); }
        nrm[tid] = sqrtf(s);
    } else if (tid < CC + CO) {
        int o = tid - CC; float s = 0.f;
        for (int c = 0; c < CC; ++c) { float v = w2[c * CO + o]; s = fmaf(v, v, s); }
        nrm[tid] = sqrtf(s);
    }
    __syncthreads();
    if (tid < CC * KNN) w1n[tid >> 4][tid & 15] = w1[tid] / nrm[tid >> 4];
    if (tid < CC * CO)  w2n[tid >> 4][tid & 15] = w2[tid] / nrm[CC + (tid & 15)];
    // visibility to epilogue covered by the scan's per-tile barriers

    const int c16 = lane & 15, g = lane >> 4;

    // ---- A-fragment: block's 16 rows x (-2), resident (4 VGPR) ----
    // A[m][k]: m = lane&15 -> row, k-octet = lane>>4  (layout confirmed R8)
    f16x8 af;
    {
        uint4 rv = *(const uint4*)(xcb + (size_t)(n0 + c16) * DF + g * 8);
        const __half2 m2 = __floats2half2_rn(-2.f, -2.f);
        uint4 sc;
        sc.x = __builtin_bit_cast(unsigned, __hmul2(__builtin_bit_cast(__half2, rv.x), m2));
        sc.y = __builtin_bit_cast(unsigned, __hmul2(__builtin_bit_cast(__half2, rv.y), m2));
        sc.z = __builtin_bit_cast(unsigned, __hmul2(__builtin_bit_cast(__half2, rv.z), m2));
        sc.w = __builtin_bit_cast(unsigned, __hmul2(__builtin_bit_cast(__half2, rv.w), m2));
        af = __builtin_bit_cast(f16x8, sc);
    }

    // ---- selection state: 2 rows per wave (R7's proven load) ----
    unsigned run[2] = {0xFFFFFFFFu, 0xFFFFFFFFu};
    unsigned T[2]   = {0xFFFFFFFFu, 0xFFFFFFFFu};
    int base[2] = {0, 0}, cnt[2] = {0, 0};
    unsigned* ffp[2] = { &fifo[wave][0][0], &fifo[wave][1][0] };

    auto accept = [&](unsigned key, unsigned& rn, unsigned& Th,
                      int& bs, int& ct, unsigned* ff) {
        bool acc = key < Th;
        unsigned long long bal = __ballot(acc);
        if (bal) {                               // wave-uniform
            int pos = ct + (int)__popcll(bal & ((1ull << lane) - 1ull));
            if (acc) ff[(bs + pos) & (FIFO_N - 1)] = key;
            ct += (int)__popcll(bal);
            __builtin_amdgcn_wave_barrier();
            asm volatile("" ::: "memory");
            if (ct >= 64) {
                unsigned bk = ff[(bs + lane) & (FIFO_N - 1)];
                bs += 64; ct -= 64;
                merge_batch(rn, bk, lane);
                Th = __shfl(rn, 63);
            }
        }
    };

    // ---- pipelined scan: this wave's own 16-cand subtile per tile ----
    // B[k][n]: n = lane&15 -> cand (cs + c16), k-octet = g. No LDS staging:
    // contiguous 1KB/wave global read, zero cross-wave reuse by construction.
    const int cs = wave * 16;
    f16x8 bf_cur = *(const f16x8*)(xcb + (size_t)(cs + c16) * DF + g * 8);
    float  sq_cur = sqb[cs + c16];
    f16x8 bf_nxt = bf_cur; float sq_nxt = sq_cur;

#pragma unroll 1
    for (int i = 0; i < NT; ++i) {
        const int par = i & 1, nxt = par ^ 1;

        if (i + 1 < NT) {                        // prefetch (hidden)
            int tc = (i + 1) * TILE + cs + c16;
            bf_nxt = *(const f16x8*)(xcb + (size_t)tc * DF + g * 8);
            sq_nxt = sqb[tc];
        }

        // MFMA: D[row = 4g+j][cand = cs+c16] = sq[cand] - 2*dot(row,cand)
        f32x4 cf = {sq_cur, sq_cur, sq_cur, sq_cur};
        f32x4 pr = __builtin_amdgcn_mfma_f32_16x16x32_f16(af, bf_cur, cf, 0, 0, 0);
        {
            float* dw = &Dl[par][(4 * g) * DSTR + cs + c16];
            dw[0 * DSTR] = pr[0];
            dw[1 * DSTR] = pr[1];
            dw[2 * DSTR] = pr[2];
            dw[3 * DSTR] = pr[3];
        }

        // selection on tile i-1 (all waves' Dl writes barrier'd)
        if (i > 0) {
            const int t0 = (i - 1) * TILE;
#pragma unroll
            for (int rr = 0; rr < 2; ++rr) {
                const int growr = wave * 2 + rr;
#pragma unroll
                for (int p = 0; p < 2; ++p) {
                    int c = p * 64 + lane;
                    float d = Dl[nxt][growr * DSTR + c];
                    unsigned key = (sortable32(d) & 0xFFFFF000u)
                                 | (unsigned)(t0 + c);
                    accept(key, run[rr], T[rr], base[rr], cnt[rr], ffp[rr]);
                }
            }
        }
        __syncthreads();
        bf_cur = bf_nxt; sq_cur = sq_nxt;
    }

    // ---- final tile's selection ----
    {
        const int par = (NT - 1) & 1;
        const int t0 = (NT - 1) * TILE;
#pragma unroll
        for (int rr = 0; rr < 2; ++rr) {
            const int growr = wave * 2 + rr;
#pragma unroll
            for (int p = 0; p < 2; ++p) {
                int c = p * 64 + lane;
                float d = Dl[par][growr * DSTR + c];
                unsigned key = (sortable32(d) & 0xFFFFF000u)
                             | (unsigned)(t0 + c);
                accept(key, run[rr], T[rr], base[rr], cnt[rr], ffp[rr]);
            }
        }
    }

    // ---- drain + canonical re-rank + emit (verified) ----
#pragma unroll
    for (int rr = 0; rr < 2; ++rr) {
        if (cnt[rr] > 0) {
            unsigned bk = (lane < cnt[rr])
                        ? ffp[rr][(base[rr] + lane) & (FIFO_N - 1)] : 0xFFFFFFFFu;
            merge_batch(run[rr], bk, lane);
        }
        rerank_and_emit(run[rr], n0 + wave * 2 + rr, xb, w1n, w2n, out, b, lane);
    }
}

extern "C" void kernel_launch(void* const* d_in, const int* in_sizes, int n_in,
                              void* d_out, int out_size, void* d_ws, size_t ws_size,
                              hipStream_t stream) {
    const float* x  = (const float*)d_in[0];
    const float* w1 = (const float*)d_in[1];
    const float* w2 = (const float*)d_in[2];
    float* out = (float*)d_out;

    float*  sq = (float*)d_ws;                                  // 64 KB
    __half* xh = (__half*)((char*)d_ws + (size_t)NB * NPTS * sizeof(float)); // 1 MB

    prep_kernel<<<NB * NPTS / 256, 256, 0, stream>>>(x, sq, xh);
    wfm_kernel<<<NB * (NPTS / 16), 512, 0, stream>>>(x, xh, sq, w1, w2, out);
}